// Round 10
// baseline (150.010 us; speedup 1.0000x reference)
//
#include <hip/hip_runtime.h>

#define ROWS 8192
#define COLS 8192
#define BR 128
#define BC 128
#define TILE_C 256                       // two quant blocks per WG tile
#define NTC (COLS / TILE_C)              // 32 tile-cols
#define NWG ((ROWS / BR) * NTC)          // 2048 workgroups

typedef float f32x4 __attribute__((ext_vector_type(4)));

// Fused: one 256-thread workgroup per 128x256 tile (2 quant blocks side by side).
// Each 64-lane wave reads/writes 1KB contiguous per row (max wave64 burst).
// Lanes 0-31 cover the left 128-col block, lanes 32-63 the right block.
__global__ __launch_bounds__(256) void observer_block_qparams(
    const float* __restrict__ in,
    float* __restrict__ scale_out,
    float* __restrict__ zp_out) {

    const int bidx = blockIdx.x;
    const int brow = bidx >> 5;          // 0..63
    const int bcp  = bidx & 31;          // 0..31 (tile col)
    const int t    = threadIdx.x;
    const int lane = t & 63;
    const int wave = t >> 6;             // 0..3
    const int c4   = lane * 4;           // 0..252 within tile
    const int blk  = lane >> 5;          // 0=left block, 1=right block

    const size_t base = (size_t)(brow * BR) * COLS + (size_t)(bcp * TILE_C);
    const float* src = in + base;

    // Sweep: 4 waves x 1 row each = 4 rows / iter; 32 iters covers 128 rows.
    float vmin = INFINITY;
    float vmax = -INFINITY;
    #pragma unroll 8
    for (int i = 0; i < 32; ++i) {
        const int row = i * 4 + wave;
        const f32x4 v = __builtin_nontemporal_load(
            reinterpret_cast<const f32x4*>(src + (size_t)row * COLS + c4));
        vmin = fminf(vmin, fminf(fminf(v.x, v.y), fminf(v.z, v.w)));
        vmax = fmaxf(vmax, fmaxf(fmaxf(v.x, v.y), fmaxf(v.z, v.w)));
    }

    // Butterfly within each 32-lane half (per quant block).
    #pragma unroll
    for (int o = 16; o > 0; o >>= 1) {
        vmin = fminf(vmin, __shfl_xor(vmin, o));
        vmax = fmaxf(vmax, __shfl_xor(vmax, o));
    }

    __shared__ float smin[4][2], smax[4][2];
    __shared__ float s_scale[2], s_zp[2];
    if (lane == 0)       { smin[wave][0] = vmin; smax[wave][0] = vmax; }
    else if (lane == 32) { smin[wave][1] = vmin; smax[wave][1] = vmax; }
    __syncthreads();

    if (t < 2) {
        const float bmin = fminf(fminf(smin[0][t], smin[1][t]),
                                 fminf(smin[2][t], smin[3][t]));
        const float bmax = fmaxf(fmaxf(smax[0][t], smax[1][t]),
                                 fmaxf(smax[2][t], smax[3][t]));
        const float rng = bmax - bmin;
        float scale, zp;
        if (rng == 0.0f) {
            scale = 1.0f;
            zp = 0.0f;
        } else {
            scale = rng / 255.0f;                            // exact fp32 div, matches jax
            zp = (float)(int)rintf(-128.0f - bmin / scale);  // nearest-even = jnp.round
        }
        s_scale[t] = scale;
        s_zp[t] = zp;
    }
    __syncthreads();

    const float sc = s_scale[blk];
    const float z  = s_zp[blk];
    const f32x4 sv = {sc, sc, sc, sc};
    const f32x4 zv = {z, z, z, z};

    float* so = scale_out + base;
    float* zo = zp_out + base;
    #pragma unroll 8
    for (int i = 0; i < 32; ++i) {
        const int row = i * 4 + wave;
        const size_t off = (size_t)row * COLS + c4;
        __builtin_nontemporal_store(sv, reinterpret_cast<f32x4*>(so + off));
        __builtin_nontemporal_store(zv, reinterpret_cast<f32x4*>(zo + off));
    }
}

extern "C" void kernel_launch(void* const* d_in, const int* in_sizes, int n_in,
                              void* d_out, int out_size, void* d_ws, size_t ws_size,
                              hipStream_t stream) {
    const float* in = (const float*)d_in[0];
    float* out = (float*)d_out;
    float* scale_out = out;
    float* zp_out = out + (size_t)ROWS * COLS;

    observer_block_qparams<<<dim3(NWG), dim3(256), 0, stream>>>(
        in, scale_out, zp_out);
}

// Round 11
// 119.097 us; speedup vs baseline: 1.2596x; 1.2596x over previous
//
#include <hip/hip_runtime.h>

#define ROWS 8192
#define COLS 8192
#define BR 128
#define BC 128
#define NBC (COLS / BC)   // 64 blocks per row of blocks

typedef float f32x4 __attribute__((ext_vector_type(4)));

// Fused: one 256-thread workgroup per 128x128 block.
// Phase 1: block min/max reduction (cached loads). Phase 2: broadcast write (NT stores).
__global__ __launch_bounds__(256) void observer_block_qparams(
    const float* __restrict__ in,
    float* __restrict__ scale_out,
    float* __restrict__ zp_out) {

    const int bidx = blockIdx.x;
    const int brow = bidx / NBC;
    const int bcol = bidx % NBC;
    const int t = threadIdx.x;

    const size_t block_base = (size_t)(brow * BR) * COLS + (size_t)(bcol * BC);
    const float* base = in + block_base;

    // Each sweep: 256 threads x 4 floats = 1024 floats = 8 rows of 128.
    const int rofs = t >> 5;          // 0..7 (row within 8-row sweep)
    const int c4   = (t & 31) * 4;    // 0..124 (col, float4-aligned)

    float vmin = INFINITY;
    float vmax = -INFINITY;
    #pragma unroll
    for (int i = 0; i < 16; ++i) {
        const f32x4 v = *reinterpret_cast<const f32x4*>(
            base + (size_t)(i * 8 + rofs) * COLS + c4);
        vmin = fminf(vmin, fminf(fminf(v.x, v.y), fminf(v.z, v.w)));
        vmax = fmaxf(vmax, fmaxf(fmaxf(v.x, v.y), fmaxf(v.z, v.w)));
    }

    // 64-lane wave butterfly reduce
    #pragma unroll
    for (int o = 32; o > 0; o >>= 1) {
        vmin = fminf(vmin, __shfl_xor(vmin, o));
        vmax = fmaxf(vmax, __shfl_xor(vmax, o));
    }

    __shared__ float smin[4], smax[4];
    __shared__ float s_scale, s_zp;
    const int wave = t >> 6;
    if ((t & 63) == 0) { smin[wave] = vmin; smax[wave] = vmax; }
    __syncthreads();

    if (t == 0) {
        const float bmin = fminf(fminf(smin[0], smin[1]), fminf(smin[2], smin[3]));
        const float bmax = fmaxf(fmaxf(smax[0], smax[1]), fmaxf(smax[2], smax[3]));
        const float rng = bmax - bmin;
        float scale, zp;
        if (rng == 0.0f) {
            scale = 1.0f;
            zp = 0.0f;
        } else {
            scale = rng / 255.0f;                            // exact fp32 div, matches jax
            zp = (float)(int)rintf(-128.0f - bmin / scale);  // nearest-even = jnp.round
        }
        s_scale = scale;
        s_zp = zp;
    }
    __syncthreads();

    const float sc = s_scale;
    const float z  = s_zp;
    const f32x4 sv = {sc, sc, sc, sc};
    const f32x4 zv = {z, z, z, z};

    float* so = scale_out + block_base;
    float* zo = zp_out + block_base;
    #pragma unroll
    for (int i = 0; i < 16; ++i) {
        const size_t off = (size_t)(i * 8 + rofs) * COLS + c4;
        __builtin_nontemporal_store(sv, reinterpret_cast<f32x4*>(so + off));
        __builtin_nontemporal_store(zv, reinterpret_cast<f32x4*>(zo + off));
    }
}

extern "C" void kernel_launch(void* const* d_in, const int* in_sizes, int n_in,
                              void* d_out, int out_size, void* d_ws, size_t ws_size,
                              hipStream_t stream) {
    const float* in = (const float*)d_in[0];
    float* out = (float*)d_out;
    float* scale_out = out;
    float* zp_out = out + (size_t)ROWS * COLS;

    observer_block_qparams<<<dim3((ROWS / BR) * NBC), dim3(256), 0, stream>>>(
        in, scale_out, zp_out);
}